// Round 6
// baseline (292.216 us; speedup 1.0000x reference)
//
#include <hip/hip_runtime.h>
#include <math.h>

#define BB 8
#define NN 8192
#define DD 128
#define MM 256
#define DVV 128
#define CHUNK 32     // tokens per chunk

#define XSCALE 0.29730177875068026f
#define INV_SQRT_M 0.0625f

typedef _Float16 f16x8 __attribute__((ext_vector_type(8)));
typedef float f32x16 __attribute__((ext_vector_type(16)));

// LDS fragment slab: 64 lanes x 8 halves, stride 520 (16B-aligned, bank-spread)
#define FR(s, l) ((s) * 520 + (l) * 8)

__device__ __forceinline__ unsigned f2ord(float f) {
    unsigned u = __float_as_uint(f);
    return (u & 0x80000000u) ? ~u : (u | 0x80000000u);
}
__device__ __forceinline__ float ord2f(unsigned u) {
    return (u & 0x80000000u) ? __uint_as_float(u & 0x7fffffffu) : __uint_as_float(~u);
}
__device__ __forceinline__ f32x16 mfma16(f16x8 a, f16x8 b, f32x16 c) {
    return __builtin_amdgcn_mfma_f32_32x32x16_f16(a, b, c, 0, 0, 0);
}
__device__ __forceinline__ int rowf(int r, int q) { return (r & 3) + 8 * (r >> 2) + 4 * q; }

// Stage X (A-operand): src row-major [32][128] fp32 -> scaled hi/lo f16 frags in R1.
__device__ __forceinline__ void stage_A(const float* __restrict__ src,
                                        _Float16* R1, float* hs, float* msk,
                                        const float* __restrict__ mrow, bool do_h) {
    const int tid = threadIdx.x;
    const int t = tid >> 3, ks = tid & 7;
    const float4* s4 = (const float4*)(src + t * DD + ks * 16);
    float x[16];
    #pragma unroll
    for (int u = 0; u < 4; ++u) {
        float4 v = s4[u];
        x[u*4+0] = v.x * XSCALE; x[u*4+1] = v.y * XSCALE;
        x[u*4+2] = v.z * XSCALE; x[u*4+3] = v.w * XSCALE;
    }
    if (do_h) {
        float p = 0.f;
        #pragma unroll
        for (int u = 0; u < 16; ++u) p += x[u] * x[u];
        p += __shfl_xor(p, 1, 64); p += __shfl_xor(p, 2, 64); p += __shfl_xor(p, 4, 64);
        if (ks == 0) { hs[t] = 0.5f * p; msk[t] = mrow[t]; }
    }
    #pragma unroll
    for (int q = 0; q < 2; ++q) {
        f16x8 h8, l8;
        #pragma unroll
        for (int j = 0; j < 8; ++j) {
            float xv = x[q*8 + j];
            _Float16 h = (_Float16)xv;
            h8[j] = h; l8[j] = (_Float16)(xv - (float)h);
        }
        *(f16x8*)&R1[FR(0*8 + ks, q*32 + t)] = h8;
        *(f16x8*)&R1[FR(1*8 + ks, q*32 + t)] = l8;
    }
}

// Stage V (B-operand): src [32 rows=k][128 cols=n] fp32 -> hi/lo frags in R1.
__device__ __forceinline__ void stage_BV(const float* __restrict__ src, _Float16* R1) {
    const int tid = threadIdx.x;
    const int t = tid >> 3, c0 = (tid & 7) * 16;
    const int ts = t >> 4, qq = (t >> 3) & 1, j = t & 7;
    const float4* s4 = (const float4*)(src + t * DVV + c0);
    #pragma unroll
    for (int u = 0; u < 4; ++u) {
        float4 v = s4[u];
        float vv[4] = {v.x, v.y, v.z, v.w};
        #pragma unroll
        for (int e = 0; e < 4; ++e) {
            int c = c0 + u*4 + e;
            int vt = c >> 5, iv = c & 31;
            _Float16 h = (_Float16)vv[e];
            R1[FR((0*4 + vt)*2 + ts, qq*32 + iv) + j] = h;
            R1[FR((1*4 + vt)*2 + ts, qq*32 + iv) + j] = (_Float16)(vv[e] - (float)h);
        }
    }
}

// ---------------------------------------------------------------------------
// pack: omega -> B-frag layout hi/lo f16 in ws; init kmaxord
// ---------------------------------------------------------------------------
__global__ __launch_bounds__(256) void pack_kernel(const float* __restrict__ omega,
                                                   _Float16* __restrict__ omh,
                                                   _Float16* __restrict__ oml,
                                                   unsigned* __restrict__ kmaxord) {
    int g = blockIdx.x * 256 + threadIdx.x;    // 0..4095
    if (g < BB) kmaxord[g] = f2ord(-INFINITY);
    int lane = g & 63, ks = (g >> 6) & 7, nt = g >> 9;
    int q = lane >> 5, i = lane & 31;
    f16x8 h8, l8;
    #pragma unroll
    for (int j = 0; j < 8; ++j) {
        float w = omega[(size_t)(ks*16 + q*8 + j) * MM + nt*32 + i];
        _Float16 h = (_Float16)w;
        h8[j] = h; l8[j] = (_Float16)(w - (float)h);
    }
    ((f16x8*)omh)[g] = h8;
    ((f16x8*)oml)[g] = l8;
}

// ---------------------------------------------------------------------------
// kmax: per-batch max of U_K (hi*hi only -- mx error cancels in the ratio)
// grid.x = 128 (2 chunks/block) -> 1024 blocks; low LDS/regs -> high residency
// ---------------------------------------------------------------------------
__global__ __launch_bounds__(256) void kmax_kernel(const float* __restrict__ K,
                                                   const _Float16* __restrict__ omh,
                                                   unsigned* __restrict__ kmaxord) {
    __shared__ __align__(16) _Float16 R1[16 * 520];
    __shared__ float wred[4];
    const int b = blockIdx.y;
    const int tid = threadIdx.x, w = tid >> 6, lane = tid & 63;
    const int w2 = 2 * w;
    const f16x8* OH = (const f16x8*)omh;

    float mx = -INFINITY;
    #pragma unroll 1
    for (int c = 0; c < 2; ++c) {
        int t0 = (blockIdx.x * 2 + c) * CHUNK;
        __syncthreads();
        stage_A(K + ((size_t)b*NN + t0) * DD, R1, nullptr, nullptr, nullptr, false);
        __syncthreads();
        f32x16 a0, a1;
        #pragma unroll
        for (int r = 0; r < 16; ++r) { a0[r] = 0.f; a1[r] = 0.f; }
        f16x8 X0 = OH[(w2*8 + 0)*64 + lane];
        f16x8 X1 = OH[((w2+1)*8 + 0)*64 + lane];
        #pragma unroll 1
        for (int ks = 0; ks < 8; ks += 2) {
            f16x8 Y0 = OH[(w2*8 + ks + 1)*64 + lane];
            f16x8 Y1 = OH[((w2+1)*8 + ks + 1)*64 + lane];
            f16x8 ah = *(const f16x8*)&R1[FR(ks, lane)];
            a0 = mfma16(ah, X0, a0);
            a1 = mfma16(ah, X1, a1);
            int k2 = (ks + 2) & 7;
            X0 = OH[(w2*8 + k2)*64 + lane];
            X1 = OH[((w2+1)*8 + k2)*64 + lane];
            f16x8 ah2 = *(const f16x8*)&R1[FR(ks + 1, lane)];
            a0 = mfma16(ah2, Y0, a0);
            a1 = mfma16(ah2, Y1, a1);
        }
        #pragma unroll
        for (int r = 0; r < 16; ++r) mx = fmaxf(mx, fmaxf(a0[r], a1[r]));
    }
    #pragma unroll
    for (int off = 1; off < 64; off <<= 1) mx = fmaxf(mx, __shfl_xor(mx, off, 64));
    if (lane == 0) wred[w] = mx;
    __syncthreads();
    if (tid == 0)
        atomicMax(kmaxord + b,
                  f2ord(fmaxf(fmaxf(wred[0], wred[1]), fmaxf(wred[2], wred[3]))));
}

// ---------------------------------------------------------------------------
// kv: U_K (3-mfma split) -> Kp -> LDS transpose -> KV = Kp^T V (3-mfma split)
// pp partial slots per batch (runtime: 64 if workspace allows, else 32).
// grid.x = pp*2 (feature-half split); each block does cpb = 256/pp chunks.
// At pp=64: 1024 blocks -> 3+ blocks/CU reachable (regs ~158, LDS 34KB).
// ---------------------------------------------------------------------------
__global__ __launch_bounds__(256) void kv_kernel(const float* __restrict__ K,
                                                 const float* __restrict__ V,
                                                 const float* __restrict__ mask,
                                                 const _Float16* __restrict__ omh,
                                                 const _Float16* __restrict__ oml,
                                                 const unsigned* __restrict__ kmaxord,
                                                 float* __restrict__ pkv,
                                                 float* __restrict__ pks,
                                                 const int pp, const int cpb) {
    __shared__ __align__(16) _Float16 R1[16 * 520];
    __shared__ __align__(16) _Float16 R2[16 * 520];
    __shared__ float hs[32], msk[32];
    const int b = blockIdx.y, bx = blockIdx.x;
    const int rest = bx >> 3;
    const int h = rest & 1;                      // feature half 0/1
    const int p = (rest >> 1) * 8 + (bx & 7);    // N-split slot 0..pp-1
    const int tid = threadIdx.x, w = tid >> 6, lane = tid & 63;
    const int i = tid & 31, q = (tid >> 5) & 1;
    const int nt = h * 4 + w;                    // this wave's 32-feature block (0..7)
    const float kmaxv = ord2f(kmaxord[b]);
    const f16x8* OH = (const f16x8*)omh;
    const f16x8* OL = (const f16x8*)oml;

    f32x16 kvacc[4];
    #pragma unroll
    for (int vt = 0; vt < 4; ++vt)
        #pragma unroll
        for (int r = 0; r < 16; ++r) kvacc[vt][r] = 0.f;
    float ksa = 0.f;

    #pragma unroll 1
    for (int c = 0; c < cpb; ++c) {
        int t0 = (p * cpb + c) * CHUNK;
        __syncthreads();
        stage_A(K + ((size_t)b*NN + t0) * DD, R1, hs, msk,
                mask + (size_t)b*NN + t0, true);
        __syncthreads();

        f32x16 a0;
        #pragma unroll
        for (int r = 0; r < 16; ++r) a0[r] = 0.f;
        f16x8 Xh = OH[(nt*8 + 0)*64 + lane];
        f16x8 Xl = OL[(nt*8 + 0)*64 + lane];
        #pragma unroll 1
        for (int ks = 0; ks < 8; ks += 2) {
            f16x8 Yh = OH[(nt*8 + ks + 1)*64 + lane];
            f16x8 Yl = OL[(nt*8 + ks + 1)*64 + lane];
            f16x8 ah = *(const f16x8*)&R1[FR(ks, lane)];
            f16x8 al = *(const f16x8*)&R1[FR(8 + ks, lane)];
            a0 = mfma16(ah, Xh, a0);
            a0 = mfma16(ah, Xl, a0);
            a0 = mfma16(al, Xh, a0);
            int k2 = (ks + 2) & 7;
            Xh = OH[(nt*8 + k2)*64 + lane];
            Xl = OL[(nt*8 + k2)*64 + lane];
            f16x8 ah2 = *(const f16x8*)&R1[FR(ks + 1, lane)];
            f16x8 al2 = *(const f16x8*)&R1[FR(8 + ks + 1, lane)];
            a0 = mfma16(ah2, Yh, a0);
            a0 = mfma16(ah2, Yl, a0);
            a0 = mfma16(al2, Yh, a0);
        }
        __syncthreads();   // R1 consumers done -> restage as V; write Kp to R2

        stage_BV(V + ((size_t)b*NN + t0) * DVV, R1);
        #pragma unroll
        for (int r = 0; r < 16; ++r) {
            int tok = rowf(r, q);
            float hh = hs[tok] + kmaxv;
            float mm = msk[tok] * INV_SQRT_M;
            float kp = (__expf(a0[r] - hh) + 1e-4f) * mm;
            ksa += kp;
            int ts = tok >> 4, qq = (tok >> 3) & 1, j = tok & 7;
            _Float16 hv = (_Float16)kp;
            R2[FR(w*2 + ts, qq*32 + i) + j] = hv;
            R2[FR(8 + w*2 + ts, qq*32 + i) + j] = (_Float16)(kp - (float)hv);
        }
        __syncthreads();

        f16x8 ah2[2], al2[2];
        #pragma unroll
        for (int ts = 0; ts < 2; ++ts) {
            ah2[ts] = *(const f16x8*)&R2[FR(w*2 + ts, lane)];
            al2[ts] = *(const f16x8*)&R2[FR(8 + w*2 + ts, lane)];
        }
        #pragma unroll
        for (int vt = 0; vt < 4; ++vt) {
            #pragma unroll
            for (int ts = 0; ts < 2; ++ts) {
                f16x8 bh = *(const f16x8*)&R1[FR(vt*2 + ts, lane)];
                f16x8 bl = *(const f16x8*)&R1[FR(8 + vt*2 + ts, lane)];
                kvacc[vt] = mfma16(ah2[ts], bh, kvacc[vt]);
                kvacc[vt] = mfma16(ah2[ts], bl, kvacc[vt]);
                kvacc[vt] = mfma16(al2[ts], bh, kvacc[vt]);
            }
        }
    }

    float* dst = pkv + ((size_t)(b * pp + p) << 15);
    #pragma unroll
    for (int vt = 0; vt < 4; ++vt)
        #pragma unroll
        for (int r = 0; r < 16; ++r) {
            int feat = nt*32 + rowf(r, q);
            dst[feat * DVV + vt*32 + i] = kvacc[vt][r];
        }
    {
        float s = ksa + __shfl_xor(ksa, 32, 64);
        if (q == 0) pks[(size_t)(b * pp + p) * MM + nt*32 + i] = s;
    }
}

// ---------------------------------------------------------------------------
// reduce: sum pp partials -> ksum fp32 + KV as hi/lo f16 B-frags (global)
// ---------------------------------------------------------------------------
__global__ __launch_bounds__(256) void reduce_kernel(const float* __restrict__ pkv,
                                                     const float* __restrict__ pks,
                                                     float* __restrict__ ksum,
                                                     _Float16* __restrict__ kvph,
                                                     _Float16* __restrict__ kvpl,
                                                     const int pp) {
    const int b = blockIdx.y;
    int g = blockIdx.x * 256 + threadIdx.x;     // 0..32767
    float s = 0.f;
    for (int p = 0; p < pp; ++p) s += pkv[((size_t)(b * pp + p) << 15) + g];
    int f = g >> 7, v = g & 127;
    int vt = v >> 5, iv = v & 31, fs = f >> 4, qq = (f >> 3) & 1, j = f & 7;
    size_t idx = (size_t)b * 32768 + (size_t)((vt*16 + fs)*64 + qq*32 + iv)*8 + j;
    _Float16 h = (_Float16)s;
    kvph[idx] = h;
    kvpl[idx] = (_Float16)(s - (float)h);
    if (blockIdx.x == 0) {
        float ss = 0.f;
        for (int p = 0; p < pp; ++p) ss += pks[(size_t)(b * pp + p) * MM + g];
        ksum[b * MM + g] = ss;
    }
}

// ---------------------------------------------------------------------------
// out: U_Q -> per-token max -> Qp frags -> Out = Qp@KV (MFMA)
// R2 aliases R1 (LDS 34KB). grid.x = 128 -> 1024 blocks.
// __launch_bounds__(256,3): cap unified VGPR+AGPR total at 170/wave so
// 3 waves/SIMD fit (was ~176 -> 2 waves). Watch FETCH_SIZE for spill.
// ---------------------------------------------------------------------------
__global__ __launch_bounds__(256, 3) void out_kernel(const float* __restrict__ Q,
                                                     const float* __restrict__ mask,
                                                     const _Float16* __restrict__ omh,
                                                     const _Float16* __restrict__ oml,
                                                     const float* __restrict__ ksum,
                                                     const _Float16* __restrict__ kvph,
                                                     const _Float16* __restrict__ kvpl,
                                                     float* __restrict__ out) {
    __shared__ __align__(16) _Float16 R2[32 * 520];   // slabs 0-15 double as R1
    __shared__ float hs[32], msk[32], wmax[4][32], norms[32];
    const int b = blockIdx.y;
    const int tid = threadIdx.x, w = tid >> 6, lane = tid & 63;
    const int i = tid & 31, q = (tid >> 5) & 1;
    const int w2 = 2 * w;
    const f16x8* OH = (const f16x8*)omh;
    const f16x8* OL = (const f16x8*)oml;
    const f16x8* KH = (const f16x8*)kvph + (size_t)b * 4096 + (w*16)*64 + lane;
    const f16x8* KL = (const f16x8*)kvpl + (size_t)b * 4096 + (w*16)*64 + lane;
    const float nk0 = ksum[b * MM + w2*32 + i];
    const float nk1 = ksum[b * MM + (w2+1)*32 + i];

    #pragma unroll 1
    for (int c = 0; c < 2; ++c) {
        int t0 = (blockIdx.x * 2 + c) * CHUNK;
        __syncthreads();   // prior oa reads (slabs 0-31) done before restage
        stage_A(Q + ((size_t)b*NN + t0) * DD, R2, hs, msk,
                mask + (size_t)b*NN + t0, true);
        if (tid < 32) norms[tid] = 1e-8f;
        __syncthreads();

        // --- U_Q: stream om frags from L2; reads slabs 0-15 ---
        f32x16 a0, a1;
        #pragma unroll
        for (int r = 0; r < 16; ++r) { a0[r] = 0.f; a1[r] = 0.f; }
        f16x8 X0h = OH[(w2*8 + 0)*64 + lane], X0l = OL[(w2*8 + 0)*64 + lane];
        f16x8 X1h = OH[((w2+1)*8 + 0)*64 + lane], X1l = OL[((w2+1)*8 + 0)*64 + lane];
        #pragma unroll 1
        for (int ks = 0; ks < 8; ks += 2) {
            f16x8 Y0h = OH[(w2*8 + ks + 1)*64 + lane], Y0l = OL[(w2*8 + ks + 1)*64 + lane];
            f16x8 Y1h = OH[((w2+1)*8 + ks + 1)*64 + lane], Y1l = OL[((w2+1)*8 + ks + 1)*64 + lane];
            f16x8 ah = *(const f16x8*)&R2[FR(ks, lane)];
            f16x8 al = *(const f16x8*)&R2[FR(8 + ks, lane)];
            a0 = mfma16(ah, X0h, a0); a0 = mfma16(ah, X0l, a0); a0 = mfma16(al, X0h, a0);
            a1 = mfma16(ah, X1h, a1); a1 = mfma16(ah, X1l, a1); a1 = mfma16(al, X1h, a1);
            int k2 = (ks + 2) & 7;
            X0h = OH[(w2*8 + k2)*64 + lane]; X0l = OL[(w2*8 + k2)*64 + lane];
            X1h = OH[((w2+1)*8 + k2)*64 + lane]; X1l = OL[((w2+1)*8 + k2)*64 + lane];
            f16x8 ah2 = *(const f16x8*)&R2[FR(ks + 1, lane)];
            f16x8 al2 = *(const f16x8*)&R2[FR(8 + ks + 1, lane)];
            a0 = mfma16(ah2, Y0h, a0); a0 = mfma16(ah2, Y0l, a0); a0 = mfma16(al2, Y0h, a0);
            a1 = mfma16(ah2, Y1h, a1); a1 = mfma16(ah2, Y1l, a1); a1 = mfma16(al2, Y1h, a1);
        }

        // --- per-token max across 256 feats ---
        float tm[16];
        #pragma unroll
        for (int r = 0; r < 16; ++r) tm[r] = fmaxf(a0[r], a1[r]);
        #pragma unroll
        for (int off = 1; off < 32; off <<= 1)
            #pragma unroll
            for (int r = 0; r < 16; ++r) tm[r] = fmaxf(tm[r], __shfl_xor(tm[r], off, 64));
        if (i == 0)
            #pragma unroll
            for (int r = 0; r < 16; ++r) wmax[w][rowf(r, q)] = tm[r];
        __syncthreads();   // wmax ready; also: all R1 reads done -> slabs reusable

        // --- Qp = exp(U-h-mx)+eps -> slabs 0-31; norm partial in f32 ---
        float nacc[16];
        #pragma unroll
        for (int r = 0; r < 16; ++r) {
            int tok = rowf(r, q);
            float tmax = fmaxf(fmaxf(wmax[0][tok], wmax[1][tok]),
                               fmaxf(wmax[2][tok], wmax[3][tok]));
            float hh = hs[tok] + tmax;
            float mm = msk[tok] * INV_SQRT_M;
            float qp0 = (__expf(a0[r] - hh) + 1e-4f) * mm;
            float qp1 = (__expf(a1[r] - hh) + 1e-4f) * mm;
            nacc[r] = qp0 * nk0 + qp1 * nk1;
            {
                int feat = w2*32 + i;
                int fstep = feat >> 4, fq = (i >> 3) & 1, fj = i & 7;
                _Float16 hv = (_Float16)qp0;
                R2[FR(fstep, fq*32 + tok) + fj] = hv;
                R2[FR(16 + fstep, fq*32 + tok) + fj] = (_Float16)(qp0 - (float)hv);
            }
            {
                int feat = (w2+1)*32 + i;
                int fstep = feat >> 4, fq = (i >> 3) & 1, fj = i & 7;
                _Float16 hv = (_Float16)qp1;
                R2[FR(fstep, fq*32 + tok) + fj] = hv;
                R2[FR(16 + fstep, fq*32 + tok) + fj] = (_Float16)(qp1 - (float)hv);
            }
        }
        // reduce norm partials over the 32 i-lanes (per half-wave)
        #pragma unroll
        for (int off = 1; off < 32; off <<= 1)
            #pragma unroll
            for (int r = 0; r < 16; ++r) nacc[r] += __shfl_xor(nacc[r], off, 64);
        if (i == 0)
            #pragma unroll
            for (int r = 0; r < 16; ++r) atomicAdd(&norms[rowf(r, q)], nacc[r]);
        __syncthreads();   // R2 frags + norms complete

        // --- Out = Qp @ KV: stream KV frags from L2 ---
        f32x16 oa;
        #pragma unroll
        for (int r = 0; r < 16; ++r) oa[r] = 0.f;
        f16x8 Fh = KH[0], Fl = KL[0];
        #pragma unroll 1
        for (int fs = 0; fs < 16; fs += 2) {
            f16x8 Gh = KH[(fs + 1)*64], Gl = KL[(fs + 1)*64];
            f16x8 ah = *(const f16x8*)&R2[FR(fs, lane)];
            f16x8 al = *(const f16x8*)&R2[FR(16 + fs, lane)];
            oa = mfma16(ah, Fh, oa); oa = mfma16(ah, Fl, oa); oa = mfma16(al, Fh, oa);
            int f2 = (fs + 2) & 15;
            Fh = KH[f2*64]; Fl = KL[f2*64];
            f16x8 ah2 = *(const f16x8*)&R2[FR(fs + 1, lane)];
            f16x8 al2 = *(const f16x8*)&R2[FR(16 + fs + 1, lane)];
            oa = mfma16(ah2, Gh, oa); oa = mfma16(ah2, Gl, oa); oa = mfma16(al2, Gh, oa);
        }

        float* ob = out + ((size_t)b*NN + t0) * DVV + w*32 + i;
        #pragma unroll
        for (int r = 0; r < 16; ++r) {
            int tok = rowf(r, q);
            ob[(size_t)tok * DVV] = oa[r] * __builtin_amdgcn_rcpf(norms[tok]);
        }
    }
}

extern "C" void kernel_launch(void* const* d_in, const int* in_sizes, int n_in,
                              void* d_out, int out_size, void* d_ws, size_t ws_size,
                              hipStream_t stream) {
    const float* Q     = (const float*)d_in[0];
    const float* K     = (const float*)d_in[1];
    const float* V     = (const float*)d_in[2];
    const float* mask  = (const float*)d_in[3];
    const float* omega = (const float*)d_in[4];
    float* out = (float*)d_out;

    char* ws = (char*)d_ws;
    _Float16* omh    = (_Float16*)(ws);                       // 64 KB
    _Float16* oml    = (_Float16*)(ws + (64 << 10));          // 64 KB
    unsigned* kmaxord = (unsigned*)(ws + (128 << 10));        // 32 B
    float*    ksum   = (float*)(ws + (132 << 10));            // 8 KB
    float*    pks    = (float*)(ws + (140 << 10));            // 512 KB max (pp*MM*B*4)
    _Float16* kvph   = (_Float16*)(ws + (700 << 10));         // 512 KB
    _Float16* kvpl   = (_Float16*)(ws + (1212 << 10));        // 512 KB
    float*    pkv    = (float*)(ws + (2 << 20));              // 32 or 64 MB

    // pp=64 needs 2MB header + 64MB pkv; fall back to 32 if workspace short.
    const size_t need64 = (2ull << 20) + ((size_t)BB * 64 * 32768 * 4);
    const int pp  = (ws_size >= need64) ? 64 : 32;
    const int cpb = (NN / CHUNK) / pp;   // chunks per kv block

    pack_kernel<<<16, 256, 0, stream>>>(omega, omh, oml, kmaxord);
    kmax_kernel<<<dim3(128, BB), 256, 0, stream>>>(K, omh, kmaxord);
    kv_kernel<<<dim3(pp * 2, BB), 256, 0, stream>>>(K, V, mask, omh, oml, kmaxord,
                                                    pkv, pks, pp, cpb);
    reduce_kernel<<<dim3(128, BB), 256, 0, stream>>>(pkv, pks, ksum, kvph, kvpl, pp);
    out_kernel<<<dim3(128, BB), 256, 0, stream>>>(Q, mask, omh, oml, ksum, kvph, kvpl, out);
}

// Round 7
// 263.762 us; speedup vs baseline: 1.1079x; 1.1079x over previous
//
#include <hip/hip_runtime.h>
#include <math.h>

#define BB 8
#define NN 8192
#define DD 128
#define MM 256
#define DVV 128
#define PP 32        // split-N partial slots per batch
#define CHUNK 32     // tokens per chunk

#define XSCALE 0.29730177875068026f
#define INV_SQRT_M 0.0625f

typedef _Float16 f16x8 __attribute__((ext_vector_type(8)));
typedef float f32x16 __attribute__((ext_vector_type(16)));

// LDS fragment slab: 64 lanes x 8 halves, stride 520 (16B-aligned, bank-spread)
#define FR(s, l) ((s) * 520 + (l) * 8)

__device__ __forceinline__ unsigned f2ord(float f) {
    unsigned u = __float_as_uint(f);
    return (u & 0x80000000u) ? ~u : (u | 0x80000000u);
}
__device__ __forceinline__ float ord2f(unsigned u) {
    return (u & 0x80000000u) ? __uint_as_float(u & 0x7fffffffu) : __uint_as_float(~u);
}
__device__ __forceinline__ f32x16 mfma16(f16x8 a, f16x8 b, f32x16 c) {
    return __builtin_amdgcn_mfma_f32_32x32x16_f16(a, b, c, 0, 0, 0);
}
__device__ __forceinline__ int rowf(int r, int q) { return (r & 3) + 8 * (r >> 2) + 4 * q; }

// T14 split staging: load 16 floats/thread (row t=tid>>3, cols (tid&7)*16..+16)
__device__ __forceinline__ void loadX16(const float* __restrict__ src, float x[16]) {
    const int tid = threadIdx.x;
    const float4* s4 = (const float4*)(src + (tid >> 3) * 128 + (tid & 7) * 16);
    #pragma unroll
    for (int u = 0; u < 4; ++u) {
        float4 v = s4[u];
        x[u*4+0] = v.x; x[u*4+1] = v.y; x[u*4+2] = v.z; x[u*4+3] = v.w;
    }
}

// write part of stage_A: scale, hi/lo split, h & mask
__device__ __forceinline__ void writeA(const float xin[16], _Float16* R1,
                                       float* hs, float* msk, float mv, bool do_h) {
    const int tid = threadIdx.x;
    const int t = tid >> 3, ks = tid & 7;
    float x[16];
    #pragma unroll
    for (int u = 0; u < 16; ++u) x[u] = xin[u] * XSCALE;
    if (do_h) {
        float p = 0.f;
        #pragma unroll
        for (int u = 0; u < 16; ++u) p += x[u] * x[u];
        p += __shfl_xor(p, 1, 64); p += __shfl_xor(p, 2, 64); p += __shfl_xor(p, 4, 64);
        if (ks == 0) { hs[t] = 0.5f * p; msk[t] = mv; }
    }
    #pragma unroll
    for (int qq = 0; qq < 2; ++qq) {
        f16x8 h8, l8;
        #pragma unroll
        for (int j = 0; j < 8; ++j) {
            float xv = x[qq*8 + j];
            _Float16 h = (_Float16)xv;
            h8[j] = h; l8[j] = (_Float16)(xv - (float)h);
        }
        *(f16x8*)&R1[FR(0*8 + ks, qq*32 + t)] = h8;
        *(f16x8*)&R1[FR(1*8 + ks, qq*32 + t)] = l8;
    }
}

// write part of stage_BV: V rows -> B-frag layout (slabs 0..15 of RV)
__device__ __forceinline__ void writeV(const float xin[16], _Float16* RV) {
    const int tid = threadIdx.x;
    const int t = tid >> 3, c0 = (tid & 7) * 16;
    const int ts = t >> 4, qq = (t >> 3) & 1, j = t & 7;
    #pragma unroll
    for (int u = 0; u < 16; ++u) {
        int c = c0 + u;
        int vt = c >> 5, iv = c & 31;
        _Float16 h = (_Float16)xin[u];
        RV[FR((0*4 + vt)*2 + ts, qq*32 + iv) + j] = h;
        RV[FR((1*4 + vt)*2 + ts, qq*32 + iv) + j] = (_Float16)(xin[u] - (float)h);
    }
}

// ---------------------------------------------------------------------------
// pack: omega -> B-frag layout hi/lo f16 in ws; init kmaxord
// ---------------------------------------------------------------------------
__global__ __launch_bounds__(256) void pack_kernel(const float* __restrict__ omega,
                                                   _Float16* __restrict__ omh,
                                                   _Float16* __restrict__ oml,
                                                   unsigned* __restrict__ kmaxord) {
    int g = blockIdx.x * 256 + threadIdx.x;    // 0..4095
    if (g < BB) kmaxord[g] = f2ord(-INFINITY);
    int lane = g & 63, ks = (g >> 6) & 7, nt = g >> 9;
    int q = lane >> 5, i = lane & 31;
    f16x8 h8, l8;
    #pragma unroll
    for (int j = 0; j < 8; ++j) {
        float w = omega[(size_t)(ks*16 + q*8 + j) * MM + nt*32 + i];
        _Float16 h = (_Float16)w;
        h8[j] = h; l8[j] = (_Float16)(w - (float)h);
    }
    ((f16x8*)omh)[g] = h8;
    ((f16x8*)oml)[g] = l8;
}

// ---------------------------------------------------------------------------
// kmax: per-batch max of U_K (hi*hi only -- mx error cancels in the ratio)
// ---------------------------------------------------------------------------
__global__ __launch_bounds__(256) void kmax_kernel(const float* __restrict__ K,
                                                   const _Float16* __restrict__ omh,
                                                   unsigned* __restrict__ kmaxord) {
    __shared__ __align__(16) _Float16 R1[16 * 520];
    __shared__ float wred[4];
    const int b = blockIdx.y;
    const int tid = threadIdx.x, w = tid >> 6, lane = tid & 63;
    const int w2 = 2 * w;
    const f16x8* OH = (const f16x8*)omh;

    float mx = -INFINITY;
    #pragma unroll 1
    for (int c = 0; c < 2; ++c) {
        int t0 = (blockIdx.x * 2 + c) * CHUNK;
        __syncthreads();
        {
            float xk[16];
            loadX16(K + ((size_t)b*NN + t0) * DD, xk);
            writeA(xk, R1, nullptr, nullptr, 0.f, false);
        }
        __syncthreads();
        f32x16 a0, a1;
        #pragma unroll
        for (int r = 0; r < 16; ++r) { a0[r] = 0.f; a1[r] = 0.f; }
        f16x8 X0 = OH[(w2*8 + 0)*64 + lane];
        f16x8 X1 = OH[((w2+1)*8 + 0)*64 + lane];
        #pragma unroll
        for (int ks = 0; ks < 8; ++ks) {
            f16x8 Y0, Y1;
            if (ks < 7) { Y0 = OH[(w2*8 + ks + 1)*64 + lane]; Y1 = OH[((w2+1)*8 + ks + 1)*64 + lane]; }
            f16x8 ah = *(const f16x8*)&R1[FR(ks, lane)];
            a0 = mfma16(ah, X0, a0);
            a1 = mfma16(ah, X1, a1);
            X0 = Y0; X1 = Y1;
        }
        #pragma unroll
        for (int r = 0; r < 16; ++r) mx = fmaxf(mx, fmaxf(a0[r], a1[r]));
    }
    #pragma unroll
    for (int off = 1; off < 64; off <<= 1) mx = fmaxf(mx, __shfl_xor(mx, off, 64));
    if (lane == 0) wred[w] = mx;
    __syncthreads();
    if (tid == 0)
        atomicMax(kmaxord + b,
                  f2ord(fmaxf(fmaxf(wred[0], wred[1]), fmaxf(wred[2], wred[3]))));
}

// ---------------------------------------------------------------------------
// kv (pipelined): iteration t runs {KV-mfma(t-1) || U-mfma(t)} in ONE fused
// phase, then stages K/V(t+1) (loads issued early, T14) + exp(t)->R2.
// 2 barriers/chunk (was 4). V double-buffered RV0/RV1; LDS 66KB -> 2 blk/CU.
// Chain split: a0a (even ks) + a0b (odd ks).
// ---------------------------------------------------------------------------
__global__ __launch_bounds__(256) void kv_kernel(const float* __restrict__ K,
                                                 const float* __restrict__ V,
                                                 const float* __restrict__ mask,
                                                 const _Float16* __restrict__ omh,
                                                 const _Float16* __restrict__ oml,
                                                 const unsigned* __restrict__ kmaxord,
                                                 float* __restrict__ pkv,
                                                 float* __restrict__ pks) {
    __shared__ __align__(16) _Float16 R1[16 * 520];
    __shared__ __align__(16) _Float16 R2[16 * 520];
    __shared__ __align__(16) _Float16 RV0[16 * 520];
    __shared__ __align__(16) _Float16 RV1[16 * 520];
    __shared__ float hs[2][32], msk[2][32];
    const int b = blockIdx.y, bx = blockIdx.x;
    const int rest = bx >> 3;
    const int h = rest & 1;                      // feature half 0/1
    const int p = (rest >> 1) * 8 + (bx & 7);    // N-split slot 0..31
    const int tid = threadIdx.x, w = tid >> 6, lane = tid & 63;
    const int i = tid & 31, q = (tid >> 5) & 1;
    const int nt = h * 4 + w;
    const int tld = tid >> 3;
    const float kmaxv = ord2f(kmaxord[b]);
    const f16x8* OH = (const f16x8*)omh;
    const f16x8* OL = (const f16x8*)oml;
    const float* Kb = K + (size_t)b * NN * DD;
    const float* Vb = V + (size_t)b * NN * DVV;
    const float* Mb = mask + (size_t)b * NN;

    f32x16 kvacc[4];
    #pragma unroll
    for (int vt = 0; vt < 4; ++vt)
        #pragma unroll
        for (int r = 0; r < 16; ++r) kvacc[vt][r] = 0.f;
    float ksa = 0.f;

    // prologue: stage chunk 0 (K -> R1, V -> RV0)
    {
        int t0 = p * 8 * CHUNK;
        float xk[16], xv[16];
        loadX16(Kb + (size_t)t0 * DD, xk);
        loadX16(Vb + (size_t)t0 * DVV, xv);
        float mv = Mb[t0 + tld];
        writeA(xk, R1, hs[0], msk[0], mv, true);
        writeV(xv, RV0);
    }
    __syncthreads();

    #pragma unroll 1
    for (int t = 0; t < 8; ++t) {
        const bool pre = (t + 1 < 8);
        float xk[16], xv[16], mv = 0.f;
        if (pre) {   // A: issue next-chunk loads early (T14)
            int t1 = (p * 8 + t + 1) * CHUNK;
            loadX16(Kb + (size_t)t1 * DD, xk);
            loadX16(Vb + (size_t)t1 * DVV, xv);
            mv = Mb[t1 + tld];
        }
        _Float16* RVprev = (t & 1) ? RV0 : RV1;   // V(t-1); becomes V(t+1)

        // B: fused MFMA phase: U(t) from R1; KV(t-1) from R2 + RVprev
        f32x16 a0a, a0b;
        #pragma unroll
        for (int r = 0; r < 16; ++r) { a0a[r] = 0.f; a0b[r] = 0.f; }
        f16x8 kh0, kl0, kh1, kl1;
        if (t > 0) {
            kh0 = *(const f16x8*)&R2[FR(w*2 + 0, lane)];
            kl0 = *(const f16x8*)&R2[FR(8 + w*2 + 0, lane)];
            kh1 = *(const f16x8*)&R2[FR(w*2 + 1, lane)];
            kl1 = *(const f16x8*)&R2[FR(8 + w*2 + 1, lane)];
        }
        f16x8 Xh = OH[(nt*8 + 0)*64 + lane];
        f16x8 Xl = OL[(nt*8 + 0)*64 + lane];
        #pragma unroll
        for (int s = 0; s < 8; ++s) {
            f16x8 Yh, Yl;
            if (s < 7) { Yh = OH[(nt*8 + s + 1)*64 + lane]; Yl = OL[(nt*8 + s + 1)*64 + lane]; }
            f16x8 ah = *(const f16x8*)&R1[FR(s, lane)];
            f16x8 al = *(const f16x8*)&R1[FR(8 + s, lane)];
            if (s & 1) {
                a0b = mfma16(ah, Xh, a0b); a0b = mfma16(ah, Xl, a0b); a0b = mfma16(al, Xh, a0b);
            } else {
                a0a = mfma16(ah, Xh, a0a); a0a = mfma16(ah, Xl, a0a); a0a = mfma16(al, Xh, a0a);
            }
            if (t > 0) {
                const int vt = s >> 1, ts = s & 1;
                f16x8 kh = ts ? kh1 : kh0, kl = ts ? kl1 : kl0;
                f16x8 bh = *(const f16x8*)&RVprev[FR(vt*2 + ts, lane)];
                f16x8 bl = *(const f16x8*)&RVprev[FR(8 + vt*2 + ts, lane)];
                kvacc[vt] = mfma16(kh, bh, kvacc[vt]);
                kvacc[vt] = mfma16(kh, bl, kvacc[vt]);
                kvacc[vt] = mfma16(kl, bh, kvacc[vt]);
            }
            Xh = Yh; Xl = Yl;
        }
        __syncthreads();   // sync1: R1/R2/RVprev reads done

        // D: write next-chunk staging; exp(t) -> R2
        if (pre) {
            writeA(xk, R1, hs[(t+1)&1], msk[(t+1)&1], mv, true);
            writeV(xv, RVprev);
        }
        const float* hsv = hs[t & 1];
        const float* mskv = msk[t & 1];
        #pragma unroll
        for (int r = 0; r < 16; ++r) {
            int tok = rowf(r, q);
            float hh = hsv[tok] + kmaxv;
            float mm = mskv[tok] * INV_SQRT_M;
            float kp = (__expf((a0a[r] + a0b[r]) - hh) + 1e-4f) * mm;
            ksa += kp;
            int ts = tok >> 4, qq = (tok >> 3) & 1, j = tok & 7;
            _Float16 hv = (_Float16)kp;
            R2[FR(w*2 + ts, qq*32 + i) + j] = hv;
            R2[FR(8 + w*2 + ts, qq*32 + i) + j] = (_Float16)(kp - (float)hv);
        }
        __syncthreads();   // sync2: R2(t), R1(t+1), RV(t+1) ready
    }

    // epilogue: KV(7) from R2 + RV1
    {
        f16x8 kh0 = *(const f16x8*)&R2[FR(w*2 + 0, lane)];
        f16x8 kl0 = *(const f16x8*)&R2[FR(8 + w*2 + 0, lane)];
        f16x8 kh1 = *(const f16x8*)&R2[FR(w*2 + 1, lane)];
        f16x8 kl1 = *(const f16x8*)&R2[FR(8 + w*2 + 1, lane)];
        #pragma unroll
        for (int vt = 0; vt < 4; ++vt) {
            #pragma unroll
            for (int ts = 0; ts < 2; ++ts) {
                f16x8 kh = ts ? kh1 : kh0, kl = ts ? kl1 : kl0;
                f16x8 bh = *(const f16x8*)&RV1[FR(vt*2 + ts, lane)];
                f16x8 bl = *(const f16x8*)&RV1[FR(8 + vt*2 + ts, lane)];
                kvacc[vt] = mfma16(kh, bh, kvacc[vt]);
                kvacc[vt] = mfma16(kh, bl, kvacc[vt]);
                kvacc[vt] = mfma16(kl, bh, kvacc[vt]);
            }
        }
    }

    float* dst = pkv + ((size_t)(b * PP + p) << 15);
    #pragma unroll
    for (int vt = 0; vt < 4; ++vt)
        #pragma unroll
        for (int r = 0; r < 16; ++r) {
            int feat = nt*32 + rowf(r, q);
            dst[feat * DVV + vt*32 + i] = kvacc[vt][r];
        }
    {
        float s = ksa + __shfl_xor(ksa, 32, 64);
        if (q == 0) pks[(size_t)(b * PP + p) * MM + nt*32 + i] = s;
    }
}

// ---------------------------------------------------------------------------
// reduce: sum PP partials -> ksum fp32 + KV as hi/lo f16 B-frags (global)
// ---------------------------------------------------------------------------
__global__ __launch_bounds__(256) void reduce_kernel(const float* __restrict__ pkv,
                                                     const float* __restrict__ pks,
                                                     float* __restrict__ ksum,
                                                     _Float16* __restrict__ kvph,
                                                     _Float16* __restrict__ kvpl) {
    const int b = blockIdx.y;
    int g = blockIdx.x * 256 + threadIdx.x;     // 0..32767
    float s = 0.f;
    for (int p = 0; p < PP; ++p) s += pkv[((size_t)(b * PP + p) << 15) + g];
    int f = g >> 7, v = g & 127;
    int vt = v >> 5, iv = v & 31, fs = f >> 4, qq = (f >> 3) & 1, j = f & 7;
    size_t idx = (size_t)b * 32768 + (size_t)((vt*16 + fs)*64 + qq*32 + iv)*8 + j;
    _Float16 h = (_Float16)s;
    kvph[idx] = h;
    kvpl[idx] = (_Float16)(s - (float)h);
    if (blockIdx.x == 0) {
        float ss = 0.f;
        for (int p = 0; p < PP; ++p) ss += pks[(size_t)(b * PP + p) * MM + g];
        ksum[b * MM + g] = ss;
    }
}

// ---------------------------------------------------------------------------
// out (pipelined): iteration c runs {PV(c-1) || U_Q(c)} fused (96 MFMAs/phase,
// oa/ob chain split), store(c-1), tmax(c), then stage Q(c+1) (T14) + exp->R2.
// 2 barriers/chunk. Norms via race-free per-wave nws partials (no atomics).
// Loop runs cpb+1 iters; c==cpb does PV/store only. LDS 52KB -> 2 blk/CU.
// ---------------------------------------------------------------------------
__global__ __launch_bounds__(256) void out_kernel(const float* __restrict__ Q,
                                                  const float* __restrict__ mask,
                                                  const _Float16* __restrict__ omh,
                                                  const _Float16* __restrict__ oml,
                                                  const float* __restrict__ ksum,
                                                  const _Float16* __restrict__ kvph,
                                                  const _Float16* __restrict__ kvpl,
                                                  float* __restrict__ out) {
    __shared__ __align__(16) _Float16 R1[16 * 520];
    __shared__ __align__(16) _Float16 R2[32 * 520];
    __shared__ float hs[2][32], msk[2][32], wmax[4][32], nws[2][4][32];
    const int b = blockIdx.y;
    const int tid = threadIdx.x, w = tid >> 6, lane = tid & 63;
    const int i = tid & 31, q = (tid >> 5) & 1;
    const int w2 = 2 * w;
    const int tld = tid >> 3;
    const f16x8* OH = (const f16x8*)omh;
    const f16x8* OL = (const f16x8*)oml;
    const f16x8* KH = (const f16x8*)kvph + (size_t)b * 4096 + (w*16)*64 + lane;
    const f16x8* KL = (const f16x8*)kvpl + (size_t)b * 4096 + (w*16)*64 + lane;
    const float nk0 = ksum[b * MM + w2*32 + i];
    const float nk1 = ksum[b * MM + (w2+1)*32 + i];
    const float* Qb = Q + (size_t)b * NN * DD;
    const float* Mb = mask + (size_t)b * NN;
    const int base = blockIdx.x * 4;

    // prologue: stage Q chunk 0
    {
        float xq[16];
        loadX16(Qb + (size_t)(base * CHUNK) * DD, xq);
        float mv = Mb[base * CHUNK + tld];
        writeA(xq, R1, hs[0], msk[0], mv, true);
    }
    __syncthreads();

    #pragma unroll 1
    for (int c = 0; c < 5; ++c) {
        const bool doU  = (c < 4);
        const bool doPV = (c > 0);
        const bool pre  = (c + 1 < 4);
        float xq[16], mv = 0.f;
        if (pre) {   // A: issue next-chunk Q loads early (T14)
            int t1 = (base + c + 1) * CHUNK;
            loadX16(Qb + (size_t)t1 * DD, xq);
            mv = Mb[t1 + tld];
        }

        // B: fused MFMA phase: U_Q(c) from R1 + om stream; PV(c-1) from R2 + KV stream
        f32x16 a0, a1, oa, ob;
        #pragma unroll
        for (int r = 0; r < 16; ++r) { a0[r] = 0.f; a1[r] = 0.f; oa[r] = 0.f; ob[r] = 0.f; }
        f16x8 X0h, X0l, X1h, X1l, F0h, F0l, F1h, F1l;
        if (doU) {
            X0h = OH[(w2*8 + 0)*64 + lane];     X0l = OL[(w2*8 + 0)*64 + lane];
            X1h = OH[((w2+1)*8 + 0)*64 + lane]; X1l = OL[((w2+1)*8 + 0)*64 + lane];
        }
        if (doPV) {
            F0h = KH[0*64]; F0l = KL[0*64];
            F1h = KH[1*64]; F1l = KL[1*64];
        }
        #pragma unroll
        for (int s = 0; s < 8; ++s) {
            f16x8 Y0h, Y0l, Y1h, Y1l, G0h, G0l, G1h, G1l;
            if (s < 7) {
                if (doU) {
                    Y0h = OH[(w2*8 + s + 1)*64 + lane];     Y0l = OL[(w2*8 + s + 1)*64 + lane];
                    Y1h = OH[((w2+1)*8 + s + 1)*64 + lane]; Y1l = OL[((w2+1)*8 + s + 1)*64 + lane];
                }
                if (doPV) {
                    G0h = KH[(2*s + 2)*64]; G0l = KL[(2*s + 2)*64];
                    G1h = KH[(2*s + 3)*64]; G1l = KL[(2*s + 3)*64];
                }
            }
            if (doU) {
                f16x8 ah = *(const f16x8*)&R1[FR(s, lane)];
                f16x8 al = *(const f16x8*)&R1[FR(8 + s, lane)];
                a0 = mfma16(ah, X0h, a0); a0 = mfma16(ah, X0l, a0); a0 = mfma16(al, X0h, a0);
                a1 = mfma16(ah, X1h, a1); a1 = mfma16(ah, X1l, a1); a1 = mfma16(al, X1h, a1);
            }
            if (doPV) {
                f16x8 ph0 = *(const f16x8*)&R2[FR(2*s, lane)];
                f16x8 pl0 = *(const f16x8*)&R2[FR(16 + 2*s, lane)];
                oa = mfma16(ph0, F0h, oa); oa = mfma16(ph0, F0l, oa); oa = mfma16(pl0, F0h, oa);
                f16x8 ph1 = *(const f16x8*)&R2[FR(2*s + 1, lane)];
                f16x8 pl1 = *(const f16x8*)&R2[FR(16 + 2*s + 1, lane)];
                ob = mfma16(ph1, F1h, ob); ob = mfma16(ph1, F1l, ob); ob = mfma16(pl1, F1h, ob);
            }
            X0h = Y0h; X0l = Y0l; X1h = Y1h; X1l = Y1l;
            F0h = G0h; F0l = G0l; F1h = G1h; F1l = G1l;
        }

        // C: store out(c-1) with race-free norm partials
        if (doPV) {
            const int pb = (c - 1) & 1;
            int tp = (base + c - 1) * CHUNK;
            float* obp = out + ((size_t)b*NN + tp) * DVV + w*32 + i;
            #pragma unroll
            for (int r = 0; r < 16; ++r) {
                int tok = rowf(r, q);
                float nrm = nws[pb][0][tok] + nws[pb][1][tok]
                          + nws[pb][2][tok] + nws[pb][3][tok] + 1e-8f;
                obp[(size_t)tok * DVV] = (oa[r] + ob[r]) * __builtin_amdgcn_rcpf(nrm);
            }
        }

        // D: per-token max across this wave's 64 features
        if (doU) {
            float tm[16];
            #pragma unroll
            for (int r = 0; r < 16; ++r) tm[r] = fmaxf(a0[r], a1[r]);
            #pragma unroll
            for (int off = 1; off < 32; off <<= 1)
                #pragma unroll
                for (int r = 0; r < 16; ++r) tm[r] = fmaxf(tm[r], __shfl_xor(tm[r], off, 64));
            if (i == 0)
                #pragma unroll
                for (int r = 0; r < 16; ++r) wmax[w][rowf(r, q)] = tm[r];
        }
        __syncthreads();   // sync1: R1/R2 reads done; wmax visible

        // E: write Q(c+1) staging; exp(c) -> R2; norm partials -> nws
        if (pre) writeA(xq, R1, hs[(c+1)&1], msk[(c+1)&1], mv, true);
        if (doU) {
            const float* hsv = hs[c & 1];
            const float* mskv = msk[c & 1];
            float nacc[16];
            #pragma unroll
            for (int r = 0; r < 16; ++r) {
                int tok = rowf(r, q);
                float tmax = fmaxf(fmaxf(wmax[0][tok], wmax[1][tok]),
                                   fmaxf(wmax[2][tok], wmax[3][tok]));
                float hh = hsv[tok] + tmax;
                float mm = mskv[tok] * INV_SQRT_M;
                float qp0 = (__expf(a0[r] - hh) + 1e-4f) * mm;
                float qp1 = (__expf(a1[r] - hh) + 1e-4f) * mm;
                nacc[r] = qp0 * nk0 + qp1 * nk1;
                {
                    int fstep = (w2*32 + i) >> 4, fq = (i >> 3) & 1, fj = i & 7;
                    _Float16 hv = (_Float16)qp0;
                    R2[FR(fstep, fq*32 + tok) + fj] = hv;
                    R2[FR(16 + fstep, fq*32 + tok) + fj] = (_Float16)(qp0 - (float)hv);
                }
                {
                    int fstep = ((w2+1)*32 + i) >> 4, fq = (i >> 3) & 1, fj = i & 7;
                    _Float16 hv = (_Float16)qp1;
                    R2[FR(fstep, fq*32 + tok) + fj] = hv;
                    R2[FR(16 + fstep, fq*32 + tok) + fj] = (_Float16)(qp1 - (float)hv);
                }
            }
            #pragma unroll
            for (int off = 1; off < 32; off <<= 1)
                #pragma unroll
                for (int r = 0; r < 16; ++r) nacc[r] += __shfl_xor(nacc[r], off, 64);
            if (i == 0)
                #pragma unroll
                for (int r = 0; r < 16; ++r) nws[c & 1][w][rowf(r, q)] = nacc[r];
        }
        __syncthreads();   // sync2: R2(c), nws(c), R1(c+1) ready
    }
}

extern "C" void kernel_launch(void* const* d_in, const int* in_sizes, int n_in,
                              void* d_out, int out_size, void* d_ws, size_t ws_size,
                              hipStream_t stream) {
    const float* Q     = (const float*)d_in[0];
    const float* K     = (const float*)d_in[1];
    const float* V     = (const float*)d_in[2];
    const float* mask  = (const float*)d_in[3];
    const float* omega = (const float*)d_in[4];
    float* out = (float*)d_out;

    char* ws = (char*)d_ws;
    _Float16* omh    = (_Float16*)(ws);                       // 64 KB
    _Float16* oml    = (_Float16*)(ws + (64 << 10));          // 64 KB
    unsigned* kmaxord = (unsigned*)(ws + (128 << 10));        // 32 B
    float*    ksum   = (float*)(ws + (132 << 10));            // 8 KB
    float*    pks    = (float*)(ws + (140 << 10));            // 256 KB
    _Float16* kvph   = (_Float16*)(ws + (400 << 10));         // 512 KB
    _Float16* kvpl   = (_Float16*)(ws + (912 << 10));         // 512 KB
    float*    pkv    = (float*)(ws + (2 << 20));              // 32 MB

    pack_kernel<<<16, 256, 0, stream>>>(omega, omh, oml, kmaxord);
    kmax_kernel<<<dim3(128, BB), 256, 0, stream>>>(K, omh, kmaxord);
    kv_kernel<<<dim3(64, BB), 256, 0, stream>>>(K, V, mask, omh, oml, kmaxord, pkv, pks);
    reduce_kernel<<<dim3(128, BB), 256, 0, stream>>>(pkv, pks, ksum, kvph, kvpl);
    out_kernel<<<dim3(64, BB), 256, 0, stream>>>(Q, mask, omh, oml, ksum, kvph, kvpl, out);
}

// Round 9
// 241.862 us; speedup vs baseline: 1.2082x; 1.0905x over previous
//
#include <hip/hip_runtime.h>
#include <math.h>

#define BB 8
#define NN 8192
#define DD 128
#define MM 256
#define DVV 128
#define PP 32        // split-N partial blocks per batch
#define CHUNK 32     // tokens per chunk

#define XSCALE 0.29730177875068026f
#define INV_SQRT_M 0.0625f

typedef _Float16 f16x8 __attribute__((ext_vector_type(8)));
typedef float f32x16 __attribute__((ext_vector_type(16)));

// LDS fragment slab: 64 lanes x 8 halves, stride 520 (16B-aligned, bank-spread)
#define FR(s, l) ((s) * 520 + (l) * 8)

__device__ __forceinline__ unsigned f2ord(float f) {
    unsigned u = __float_as_uint(f);
    return (u & 0x80000000u) ? ~u : (u | 0x80000000u);
}
__device__ __forceinline__ float ord2f(unsigned u) {
    return (u & 0x80000000u) ? __uint_as_float(u & 0x7fffffffu) : __uint_as_float(~u);
}
__device__ __forceinline__ f32x16 mfma16(f16x8 a, f16x8 b, f32x16 c) {
    return __builtin_amdgcn_mfma_f32_32x32x16_f16(a, b, c, 0, 0, 0);
}
__device__ __forceinline__ int rowf(int r, int q) { return (r & 3) + 8 * (r >> 2) + 4 * q; }

// Stage X (A-operand): src row-major [32][128] fp32 -> scaled hi/lo f16 frags in R1.
__device__ __forceinline__ void stage_A(const float* __restrict__ src,
                                        _Float16* R1, float* hs, float* msk,
                                        const float* __restrict__ mrow, bool do_h) {
    const int tid = threadIdx.x;
    const int t = tid >> 3, ks = tid & 7;
    const float4* s4 = (const float4*)(src + t * DD + ks * 16);
    float x[16];
    #pragma unroll
    for (int u = 0; u < 4; ++u) {
        float4 v = s4[u];
        x[u*4+0] = v.x * XSCALE; x[u*4+1] = v.y * XSCALE;
        x[u*4+2] = v.z * XSCALE; x[u*4+3] = v.w * XSCALE;
    }
    if (do_h) {
        float p = 0.f;
        #pragma unroll
        for (int u = 0; u < 16; ++u) p += x[u] * x[u];
        p += __shfl_xor(p, 1, 64); p += __shfl_xor(p, 2, 64); p += __shfl_xor(p, 4, 64);
        if (ks == 0) { hs[t] = 0.5f * p; msk[t] = mrow[t]; }
    }
    #pragma unroll
    for (int q = 0; q < 2; ++q) {
        f16x8 h8, l8;
        #pragma unroll
        for (int j = 0; j < 8; ++j) {
            float xv = x[q*8 + j];
            _Float16 h = (_Float16)xv;
            h8[j] = h; l8[j] = (_Float16)(xv - (float)h);
        }
        *(f16x8*)&R1[FR(0*8 + ks, q*32 + t)] = h8;
        *(f16x8*)&R1[FR(1*8 + ks, q*32 + t)] = l8;
    }
}

// Stage V (B-operand): src [32 rows=k][128 cols=n] fp32 -> hi/lo frags in R1.
__device__ __forceinline__ void stage_BV(const float* __restrict__ src, _Float16* R1) {
    const int tid = threadIdx.x;
    const int t = tid >> 3, c0 = (tid & 7) * 16;
    const int ts = t >> 4, qq = (t >> 3) & 1, j = t & 7;
    const float4* s4 = (const float4*)(src + t * DVV + c0);
    #pragma unroll
    for (int u = 0; u < 4; ++u) {
        float4 v = s4[u];
        float vv[4] = {v.x, v.y, v.z, v.w};
        #pragma unroll
        for (int e = 0; e < 4; ++e) {
            int c = c0 + u*4 + e;
            int vt = c >> 5, iv = c & 31;
            _Float16 h = (_Float16)vv[e];
            R1[FR((0*4 + vt)*2 + ts, qq*32 + iv) + j] = h;
            R1[FR((1*4 + vt)*2 + ts, qq*32 + iv) + j] = (_Float16)(vv[e] - (float)h);
        }
    }
}

// ---------------------------------------------------------------------------
// pack: omega -> B-frag layout hi/lo f16 in ws; init kmaxord
// ---------------------------------------------------------------------------
__global__ __launch_bounds__(256) void pack_kernel(const float* __restrict__ omega,
                                                   _Float16* __restrict__ omh,
                                                   _Float16* __restrict__ oml,
                                                   unsigned* __restrict__ kmaxord) {
    int g = blockIdx.x * 256 + threadIdx.x;    // 0..4095
    if (g < BB) kmaxord[g] = f2ord(-INFINITY);
    int lane = g & 63, ks = (g >> 6) & 7, nt = g >> 9;
    int q = lane >> 5, i = lane & 31;
    f16x8 h8, l8;
    #pragma unroll
    for (int j = 0; j < 8; ++j) {
        float w = omega[(size_t)(ks*16 + q*8 + j) * MM + nt*32 + i];
        _Float16 h = (_Float16)w;
        h8[j] = h; l8[j] = (_Float16)(w - (float)h);
    }
    ((f16x8*)omh)[g] = h8;
    ((f16x8*)oml)[g] = l8;
}

// ---------------------------------------------------------------------------
// kmax: per-batch max of U_K (hi*hi only -- mx error cancels in the ratio)
// om frags STREAMED from L2 (not register-resident) -> low VGPR, multi-wave/SIMD
// ---------------------------------------------------------------------------
__global__ __launch_bounds__(256) void kmax_kernel(const float* __restrict__ K,
                                                   const _Float16* __restrict__ omh,
                                                   unsigned* __restrict__ kmaxord) {
    __shared__ __align__(16) _Float16 R1[16 * 520];
    __shared__ float wred[4];
    const int b = blockIdx.y;
    const int tid = threadIdx.x, w = tid >> 6, lane = tid & 63;
    const int w2 = 2 * w;
    const f16x8* OH = (const f16x8*)omh;

    float mx = -INFINITY;
    #pragma unroll 1
    for (int c = 0; c < 4; ++c) {
        int t0 = (blockIdx.x * 4 + c) * CHUNK;
        __syncthreads();
        stage_A(K + ((size_t)b*NN + t0) * DD, R1, nullptr, nullptr, nullptr, false);
        __syncthreads();
        f32x16 a0, a1;
        #pragma unroll
        for (int r = 0; r < 16; ++r) { a0[r] = 0.f; a1[r] = 0.f; }
        f16x8 X0 = OH[(w2*8 + 0)*64 + lane];
        f16x8 X1 = OH[((w2+1)*8 + 0)*64 + lane];
        #pragma unroll 1
        for (int ks = 0; ks < 8; ks += 2) {
            f16x8 Y0 = OH[(w2*8 + ks + 1)*64 + lane];
            f16x8 Y1 = OH[((w2+1)*8 + ks + 1)*64 + lane];
            f16x8 ah = *(const f16x8*)&R1[FR(ks, lane)];
            a0 = mfma16(ah, X0, a0);
            a1 = mfma16(ah, X1, a1);
            int k2 = (ks + 2) & 7;
            X0 = OH[(w2*8 + k2)*64 + lane];
            X1 = OH[((w2+1)*8 + k2)*64 + lane];
            f16x8 ah2 = *(const f16x8*)&R1[FR(ks + 1, lane)];
            a0 = mfma16(ah2, Y0, a0);
            a1 = mfma16(ah2, Y1, a1);
        }
        #pragma unroll
        for (int r = 0; r < 16; ++r) mx = fmaxf(mx, fmaxf(a0[r], a1[r]));
    }
    #pragma unroll
    for (int off = 1; off < 64; off <<= 1) mx = fmaxf(mx, __shfl_xor(mx, off, 64));
    if (lane == 0) wred[w] = mx;
    __syncthreads();
    if (tid == 0)
        atomicMax(kmaxord + b,
                  f2ord(fmaxf(fmaxf(wred[0], wred[1]), fmaxf(wred[2], wred[3]))));
}

// ---------------------------------------------------------------------------
// kv: U_K (3-mfma split) -> Kp -> LDS transpose -> KV = Kp^T V (3-mfma split)
// Feature-split (2 blocks per p-slot); om frags STREAMED from L2 so only
// kvacc (64 AGPR) stays resident -> total regs/wave <=256 -> 2 waves/SIMD.
// ---------------------------------------------------------------------------
__global__ __launch_bounds__(256) void kv_kernel(const float* __restrict__ K,
                                                 const float* __restrict__ V,
                                                 const float* __restrict__ mask,
                                                 const _Float16* __restrict__ omh,
                                                 const _Float16* __restrict__ oml,
                                                 const unsigned* __restrict__ kmaxord,
                                                 float* __restrict__ pkv,
                                                 float* __restrict__ pks) {
    __shared__ __align__(16) _Float16 R1[16 * 520];
    __shared__ __align__(16) _Float16 R2[16 * 520];
    __shared__ float hs[32], msk[32];
    const int b = blockIdx.y, bx = blockIdx.x;
    const int rest = bx >> 3;
    const int h = rest & 1;                      // feature half 0/1
    const int p = (rest >> 1) * 8 + (bx & 7);    // N-split slot 0..31
    const int tid = threadIdx.x, w = tid >> 6, lane = tid & 63;
    const int i = tid & 31, q = (tid >> 5) & 1;
    const int nt = h * 4 + w;                    // this wave's 32-feature block (0..7)
    const float kmaxv = ord2f(kmaxord[b]);
    const f16x8* OH = (const f16x8*)omh;
    const f16x8* OL = (const f16x8*)oml;

    f32x16 kvacc[4];
    #pragma unroll
    for (int vt = 0; vt < 4; ++vt)
        #pragma unroll
        for (int r = 0; r < 16; ++r) kvacc[vt][r] = 0.f;
    float ksa = 0.f;

    #pragma unroll 1
    for (int c = 0; c < 8; ++c) {
        int t0 = (p * 8 + c) * CHUNK;
        __syncthreads();
        stage_A(K + ((size_t)b*NN + t0) * DD, R1, hs, msk,
                mask + (size_t)b*NN + t0, true);
        __syncthreads();

        f32x16 a0;
        #pragma unroll
        for (int r = 0; r < 16; ++r) a0[r] = 0.f;
        f16x8 Xh = OH[(nt*8 + 0)*64 + lane];
        f16x8 Xl = OL[(nt*8 + 0)*64 + lane];
        #pragma unroll 1
        for (int ks = 0; ks < 8; ks += 2) {
            f16x8 Yh = OH[(nt*8 + ks + 1)*64 + lane];
            f16x8 Yl = OL[(nt*8 + ks + 1)*64 + lane];
            f16x8 ah = *(const f16x8*)&R1[FR(ks, lane)];
            f16x8 al = *(const f16x8*)&R1[FR(8 + ks, lane)];
            a0 = mfma16(ah, Xh, a0);
            a0 = mfma16(ah, Xl, a0);
            a0 = mfma16(al, Xh, a0);
            int k2 = (ks + 2) & 7;
            Xh = OH[(nt*8 + k2)*64 + lane];
            Xl = OL[(nt*8 + k2)*64 + lane];
            f16x8 ah2 = *(const f16x8*)&R1[FR(ks + 1, lane)];
            f16x8 al2 = *(const f16x8*)&R1[FR(8 + ks + 1, lane)];
            a0 = mfma16(ah2, Yh, a0);
            a0 = mfma16(ah2, Yl, a0);
            a0 = mfma16(al2, Yh, a0);
        }
        __syncthreads();   // R1 consumers done -> restage as V; write Kp to R2

        stage_BV(V + ((size_t)b*NN + t0) * DVV, R1);
        #pragma unroll
        for (int r = 0; r < 16; ++r) {
            int tok = rowf(r, q);
            float hh = hs[tok] + kmaxv;
            float mm = msk[tok] * INV_SQRT_M;
            float kp = (__expf(a0[r] - hh) + 1e-4f) * mm;
            ksa += kp;
            int ts = tok >> 4, qq = (tok >> 3) & 1, j = tok & 7;
            _Float16 hv = (_Float16)kp;
            R2[FR(w*2 + ts, qq*32 + i) + j] = hv;
            R2[FR(8 + w*2 + ts, qq*32 + i) + j] = (_Float16)(kp - (float)hv);
        }
        __syncthreads();

        f16x8 ah2[2], al2[2];
        #pragma unroll
        for (int ts = 0; ts < 2; ++ts) {
            ah2[ts] = *(const f16x8*)&R2[FR(w*2 + ts, lane)];
            al2[ts] = *(const f16x8*)&R2[FR(8 + w*2 + ts, lane)];
        }
        #pragma unroll
        for (int vt = 0; vt < 4; ++vt) {
            #pragma unroll
            for (int ts = 0; ts < 2; ++ts) {
                f16x8 bh = *(const f16x8*)&R1[FR(vt*2 + ts, lane)];
                f16x8 bl = *(const f16x8*)&R1[FR(8 + vt*2 + ts, lane)];
                kvacc[vt] = mfma16(ah2[ts], bh, kvacc[vt]);
                kvacc[vt] = mfma16(ah2[ts], bl, kvacc[vt]);
                kvacc[vt] = mfma16(al2[ts], bh, kvacc[vt]);
            }
        }
    }

    float* dst = pkv + ((size_t)(b * PP + p) << 15);
    #pragma unroll
    for (int vt = 0; vt < 4; ++vt)
        #pragma unroll
        for (int r = 0; r < 16; ++r) {
            int feat = nt*32 + rowf(r, q);
            dst[feat * DVV + vt*32 + i] = kvacc[vt][r];
        }
    {
        float s = ksa + __shfl_xor(ksa, 32, 64);
        if (q == 0) pks[(size_t)(b * PP + p) * MM + nt*32 + i] = s;
    }
}

// ---------------------------------------------------------------------------
// reduce: sum P partials -> ksum fp32 + KV as hi/lo f16 B-frags (global)
// ---------------------------------------------------------------------------
__global__ __launch_bounds__(256) void reduce_kernel(const float* __restrict__ pkv,
                                                     const float* __restrict__ pks,
                                                     float* __restrict__ ksum,
                                                     _Float16* __restrict__ kvph,
                                                     _Float16* __restrict__ kvpl) {
    const int b = blockIdx.y;
    int g = blockIdx.x * 256 + threadIdx.x;     // 0..32767
    float s = 0.f;
    for (int p = 0; p < PP; ++p) s += pkv[((size_t)(b * PP + p) << 15) + g];
    int f = g >> 7, v = g & 127;
    int vt = v >> 5, iv = v & 31, fs = f >> 4, qq = (f >> 3) & 1, j = f & 7;
    size_t idx = (size_t)b * 32768 + (size_t)((vt*16 + fs)*64 + qq*32 + iv)*8 + j;
    _Float16 h = (_Float16)s;
    kvph[idx] = h;
    kvpl[idx] = (_Float16)(s - (float)h);
    if (blockIdx.x == 0) {
        float ss = 0.f;
        for (int p = 0; p < PP; ++p) ss += pks[(size_t)(b * PP + p) * MM + g];
        ksum[b * MM + g] = ss;
    }
}

// ---------------------------------------------------------------------------
// out: U_Q -> per-token max -> Qp frags -> Out = Qp@KV (MFMA)
// om and KV frags STREAMED from L2 (1-ahead prefetch, manual unroll-2);
// norm via f32 FMA + shuffle tree. VGPR ~116 -> spill-free 2 waves/SIMD.
// ---------------------------------------------------------------------------
__global__ __launch_bounds__(256) void out_kernel(const float* __restrict__ Q,
                                                  const float* __restrict__ mask,
                                                  const _Float16* __restrict__ omh,
                                                  const _Float16* __restrict__ oml,
                                                  const float* __restrict__ ksum,
                                                  const _Float16* __restrict__ kvph,
                                                  const _Float16* __restrict__ kvpl,
                                                  float* __restrict__ out) {
    __shared__ __align__(16) _Float16 R1[16 * 520];
    __shared__ __align__(16) _Float16 R2[32 * 520];
    __shared__ float hs[32], msk[32], wmax[4][32], norms[32];
    const int b = blockIdx.y;
    const int tid = threadIdx.x, w = tid >> 6, lane = tid & 63;
    const int i = tid & 31, q = (tid >> 5) & 1;
    const int w2 = 2 * w;
    const f16x8* OH = (const f16x8*)omh;
    const f16x8* OL = (const f16x8*)oml;
    const f16x8* KH = (const f16x8*)kvph + (size_t)b * 4096 + (w*16)*64 + lane;
    const f16x8* KL = (const f16x8*)kvpl + (size_t)b * 4096 + (w*16)*64 + lane;
    const float nk0 = ksum[b * MM + w2*32 + i];
    const float nk1 = ksum[b * MM + (w2+1)*32 + i];

    #pragma unroll 1
    for (int c = 0; c < 4; ++c) {
        int t0 = (blockIdx.x * 4 + c) * CHUNK;
        __syncthreads();
        stage_A(Q + ((size_t)b*NN + t0) * DD, R1, hs, msk,
                mask + (size_t)b*NN + t0, true);
        if (tid < 32) norms[tid] = 1e-8f;
        __syncthreads();

        // --- U_Q: stream om frags from L2 ---
        f32x16 a0, a1;
        #pragma unroll
        for (int r = 0; r < 16; ++r) { a0[r] = 0.f; a1[r] = 0.f; }
        f16x8 X0h = OH[(w2*8 + 0)*64 + lane], X0l = OL[(w2*8 + 0)*64 + lane];
        f16x8 X1h = OH[((w2+1)*8 + 0)*64 + lane], X1l = OL[((w2+1)*8 + 0)*64 + lane];
        #pragma unroll 1
        for (int ks = 0; ks < 8; ks += 2) {
            f16x8 Y0h = OH[(w2*8 + ks + 1)*64 + lane], Y0l = OL[(w2*8 + ks + 1)*64 + lane];
            f16x8 Y1h = OH[((w2+1)*8 + ks + 1)*64 + lane], Y1l = OL[((w2+1)*8 + ks + 1)*64 + lane];
            f16x8 ah = *(const f16x8*)&R1[FR(ks, lane)];
            f16x8 al = *(const f16x8*)&R1[FR(8 + ks, lane)];
            a0 = mfma16(ah, X0h, a0); a0 = mfma16(ah, X0l, a0); a0 = mfma16(al, X0h, a0);
            a1 = mfma16(ah, X1h, a1); a1 = mfma16(ah, X1l, a1); a1 = mfma16(al, X1h, a1);
            int k2 = (ks + 2) & 7;
            X0h = OH[(w2*8 + k2)*64 + lane]; X0l = OL[(w2*8 + k2)*64 + lane];
            X1h = OH[((w2+1)*8 + k2)*64 + lane]; X1l = OL[((w2+1)*8 + k2)*64 + lane];
            f16x8 ah2 = *(const f16x8*)&R1[FR(ks + 1, lane)];
            f16x8 al2 = *(const f16x8*)&R1[FR(8 + ks + 1, lane)];
            a0 = mfma16(ah2, Y0h, a0); a0 = mfma16(ah2, Y0l, a0); a0 = mfma16(al2, Y0h, a0);
            a1 = mfma16(ah2, Y1h, a1); a1 = mfma16(ah2, Y1l, a1); a1 = mfma16(al2, Y1h, a1);
        }

        // --- per-token max across 256 feats ---
        float tm[16];
        #pragma unroll
        for (int r = 0; r < 16; ++r) tm[r] = fmaxf(a0[r], a1[r]);
        #pragma unroll
        for (int off = 1; off < 32; off <<= 1)
            #pragma unroll
            for (int r = 0; r < 16; ++r) tm[r] = fmaxf(tm[r], __shfl_xor(tm[r], off, 64));
        if (i == 0)
            #pragma unroll
            for (int r = 0; r < 16; ++r) wmax[w][rowf(r, q)] = tm[r];
        __syncthreads();

        // --- Qp = exp(U-h-mx)+eps, write hi/lo frags; norm partial in f32 ---
        float nacc[16];
        #pragma unroll
        for (int r = 0; r < 16; ++r) {
            int tok = rowf(r, q);
            float tmax = fmaxf(fmaxf(wmax[0][tok], wmax[1][tok]),
                               fmaxf(wmax[2][tok], wmax[3][tok]));
            float hh = hs[tok] + tmax;
            float mm = msk[tok] * INV_SQRT_M;
            float qp0 = (__expf(a0[r] - hh) + 1e-4f) * mm;
            float qp1 = (__expf(a1[r] - hh) + 1e-4f) * mm;
            nacc[r] = qp0 * nk0 + qp1 * nk1;
            {
                int feat = w2*32 + i;
                int fstep = feat >> 4, fq = (i >> 3) & 1, fj = i & 7;
                _Float16 hv = (_Float16)qp0;
                R2[FR(fstep, fq*32 + tok) + fj] = hv;
                R2[FR(16 + fstep, fq*32 + tok) + fj] = (_Float16)(qp0 - (float)hv);
            }
            {
                int feat = (w2+1)*32 + i;
                int fstep = feat >> 4, fq = (i >> 3) & 1, fj = i & 7;
                _Float16 hv = (_Float16)qp1;
                R2[FR(fstep, fq*32 + tok) + fj] = hv;
                R2[FR(16 + fstep, fq*32 + tok) + fj] = (_Float16)(qp1 - (float)hv);
            }
        }
        // reduce norm partials over the 32 i-lanes (per half-wave)
        #pragma unroll
        for (int off = 1; off < 32; off <<= 1)
            #pragma unroll
            for (int r = 0; r < 16; ++r) nacc[r] += __shfl_xor(nacc[r], off, 64);
        if (i == 0)
            #pragma unroll
            for (int r = 0; r < 16; ++r) atomicAdd(&norms[rowf(r, q)], nacc[r]);
        __syncthreads();   // R2 frags + norms complete

        // --- Out = Qp @ KV: stream KV frags from L2 ---
        f32x16 oa;
        #pragma unroll
        for (int r = 0; r < 16; ++r) oa[r] = 0.f;
        f16x8 Fh = KH[0], Fl = KL[0];
        #pragma unroll 1
        for (int fs = 0; fs < 16; fs += 2) {
            f16x8 Gh = KH[(fs + 1)*64], Gl = KL[(fs + 1)*64];
            f16x8 ah = *(const f16x8*)&R2[FR(fs, lane)];
            f16x8 al = *(const f16x8*)&R2[FR(16 + fs, lane)];
            oa = mfma16(ah, Fh, oa); oa = mfma16(ah, Fl, oa); oa = mfma16(al, Fh, oa);
            int f2 = (fs + 2) & 15;
            Fh = KH[f2*64]; Fl = KL[f2*64];
            f16x8 ah2 = *(const f16x8*)&R2[FR(fs + 1, lane)];
            f16x8 al2 = *(const f16x8*)&R2[FR(16 + fs + 1, lane)];
            oa = mfma16(ah2, Gh, oa); oa = mfma16(ah2, Gl, oa); oa = mfma16(al2, Gh, oa);
        }

        float* ob = out + ((size_t)b*NN + t0) * DVV + w*32 + i;
        #pragma unroll
        for (int r = 0; r < 16; ++r) {
            int tok = rowf(r, q);
            ob[(size_t)tok * DVV] = oa[r] * __builtin_amdgcn_rcpf(norms[tok]);
        }
    }
}

extern "C" void kernel_launch(void* const* d_in, const int* in_sizes, int n_in,
                              void* d_out, int out_size, void* d_ws, size_t ws_size,
                              hipStream_t stream) {
    const float* Q     = (const float*)d_in[0];
    const float* K     = (const float*)d_in[1];
    const float* V     = (const float*)d_in[2];
    const float* mask  = (const float*)d_in[3];
    const float* omega = (const float*)d_in[4];
    float* out = (float*)d_out;

    char* ws = (char*)d_ws;
    _Float16* omh    = (_Float16*)(ws);                       // 64 KB
    _Float16* oml    = (_Float16*)(ws + (64 << 10));          // 64 KB
    unsigned* kmaxord = (unsigned*)(ws + (128 << 10));        // 32 B
    float*    ksum   = (float*)(ws + (132 << 10));            // 8 KB
    float*    pks    = (float*)(ws + (140 << 10));            // 256 KB
    _Float16* kvph   = (_Float16*)(ws + (400 << 10));         // 512 KB
    _Float16* kvpl   = (_Float16*)(ws + (912 << 10));         // 512 KB
    float*    pkv    = (float*)(ws + (2 << 20));              // 32 MB

    pack_kernel<<<16, 256, 0, stream>>>(omega, omh, oml, kmaxord);
    kmax_kernel<<<dim3(64, BB), 256, 0, stream>>>(K, omh, kmaxord);
    kv_kernel<<<dim3(64, BB), 256, 0, stream>>>(K, V, mask, omh, oml, kmaxord, pkv, pks);
    reduce_kernel<<<dim3(128, BB), 256, 0, stream>>>(pkv, pks, ksum, kvph, kvpl);
    out_kernel<<<dim3(64, BB), 256, 0, stream>>>(Q, mask, omh, oml, ksum, kvph, kvpl, out);
}